// Round 2
// baseline (899.429 us; speedup 1.0000x reference)
//
#include <hip/hip_runtime.h>

// HamGraphConvolution: N=100k nodes, D=64 feats, H=4 heads (DK=16), E=1.6M edges.
// xt = c1*x + c2*(x@W^T)  (Hamiltonian 4-step linear recurrence folded on host)
// GAT-style attention normalized over col, aggregated over row.
// Softmax max-subtraction skipped: shift-invariant, eps 1e-16 unreachable.
// R2: per-edge scalar work (exp/lrelu/div) hoisted out of the wave-wide
//     aggregation kernel (R1: VALUBusy 79% from 64x-redundant edge math).

#define LRELU(v) ((v) > 0.0f ? (v) : 0.2f * (v))

__global__ __launch_bounds__(256) void k_init(float* __restrict__ out,
                                              float* __restrict__ denom, int n) {
    int i = blockIdx.x * 256 + threadIdx.x;
    if (i < n * 64) out[i] = 0.0f;
    if (i < n * 4) denom[i] = 0.0f;
}

__global__ __launch_bounds__(256) void k_node(const float* __restrict__ x,
                                              const float* __restrict__ W,
                                              const float* __restrict__ a,
                                              float* __restrict__ xt,
                                              float* __restrict__ s_src,
                                              float* __restrict__ s_dst,
                                              int n, float c1, float c2) {
    __shared__ float Ws[64 * 65];  // padded: bank (lane+k)%32 -> 2-way (free)
    for (int i = threadIdx.x; i < 64 * 64; i += 256) {
        int r = i >> 6, c = i & 63;
        Ws[r * 65 + c] = W[i];
    }
    __syncthreads();
    int wave = threadIdx.x >> 6;
    int lane = threadIdx.x & 63;
    float a_s = a[lane & 15];
    float a_d = a[16 + (lane & 15)];
    int node = blockIdx.x * 4 + wave;
    if (node >= n) return;

    float xv = x[node * 64 + lane];
    // p[lane] = sum_k x[k] * W[lane][k]
    float p = 0.0f;
#pragma unroll
    for (int k = 0; k < 64; ++k) {
        float xk = __shfl(xv, k, 64);
        p = fmaf(xk, Ws[lane * 65 + k], p);
    }
    float xtv = c1 * xv + c2 * p;
    xt[node * 64 + lane] = xtv;

    // per-head (16-lane group) reductions
    float ss = xtv * a_s;
    float sd = xtv * a_d;
#pragma unroll
    for (int off = 8; off >= 1; off >>= 1) {
        ss += __shfl_xor(ss, off, 64);
        sd += __shfl_xor(sd, off, 64);
    }
    if ((lane & 15) == 0) {
        int h = lane >> 4;
        s_src[node * 4 + h] = ss;
        s_dst[node * 4 + h] = sd;
    }
}

__global__ __launch_bounds__(256) void k_denom(const int* __restrict__ row,
                                               const int* __restrict__ col,
                                               const float* __restrict__ s_src,
                                               const float* __restrict__ s_dst,
                                               float* __restrict__ denom, int e) {
    int idx = blockIdx.x * 256 + threadIdx.x;
    if (idx >= e) return;
    int r = row[idx], c = col[idx];
    float4 ss = *(const float4*)(s_src + (size_t)r * 4);
    float4 sd = *(const float4*)(s_dst + (size_t)c * 4);
    atomicAdd(&denom[c * 4 + 0], __expf(LRELU(ss.x + sd.x)));
    atomicAdd(&denom[c * 4 + 1], __expf(LRELU(ss.y + sd.y)));
    atomicAdd(&denom[c * 4 + 2], __expf(LRELU(ss.z + sd.z)));
    atomicAdd(&denom[c * 4 + 3], __expf(LRELU(ss.w + sd.w)));
}

// rden[c,h] = 1/(denom[c,h] + 1e-16): divides paid once per col, not per edge
__global__ __launch_bounds__(256) void k_rden(const float* __restrict__ denom,
                                              float* __restrict__ rden, int n4) {
    int i = blockIdx.x * 256 + threadIdx.x;
    if (i < n4) rden[i] = 1.0f / (denom[i] + 1e-16f);
}

// thread-per-edge: all scalar edge math at 1 lane/edge (was 64x redundant)
__global__ __launch_bounds__(256) void k_edgew(const int* __restrict__ row,
                                               const int* __restrict__ col,
                                               const float* __restrict__ s_src,
                                               const float* __restrict__ s_dst,
                                               const float* __restrict__ rden,
                                               float* __restrict__ w, int e) {
    int idx = blockIdx.x * 256 + threadIdx.x;
    if (idx >= e) return;
    int r = row[idx], c = col[idx];
    float4 ss = *(const float4*)(s_src + (size_t)r * 4);
    float4 sd = *(const float4*)(s_dst + (size_t)c * 4);
    float4 rd = *(const float4*)(rden + (size_t)c * 4);
    float wv = __expf(LRELU(ss.x + sd.x)) * rd.x +
               __expf(LRELU(ss.y + sd.y)) * rd.y +
               __expf(LRELU(ss.z + sd.z)) * rd.z +
               __expf(LRELU(ss.w + sd.w)) * rd.w;
    w[idx] = 0.25f * wv;
}

// wave-per-edge, lean: broadcast w, gather xt row, scatter-atomic out row
__global__ __launch_bounds__(256) void k_aggr(const int* __restrict__ row,
                                              const int* __restrict__ col,
                                              const float* __restrict__ w,
                                              const float* __restrict__ xt,
                                              float* __restrict__ out, int e) {
    int edge = blockIdx.x * 4 + (threadIdx.x >> 6);
    if (edge >= e) return;
    int lane = threadIdx.x & 63;
    int r = row[edge], c = col[edge];
    float wv = w[edge];  // same addr across wave -> broadcast
    atomicAdd(&out[(size_t)r * 64 + lane], wv * xt[(size_t)c * 64 + lane]);
}

extern "C" void kernel_launch(void* const* d_in, const int* in_sizes, int n_in,
                              void* d_out, int out_size, void* d_ws, size_t ws_size,
                              hipStream_t stream) {
    const float* x = (const float*)d_in[0];
    const int* ei = (const int*)d_in[1];
    // d_in[2] = edge_weight: unused by the reference
    const float* W = (const float*)d_in[3];
    const float* a = (const float*)d_in[4];
    int n = in_sizes[0] / 64;
    int e = in_sizes[1] / 2;
    const int* row = ei;
    const int* col = ei + e;
    float* out = (float*)d_out;

    float* xt = (float*)d_ws;                   // n*64 floats
    float* s_src = xt + (size_t)n * 64;         // n*4
    float* s_dst = s_src + (size_t)n * 4;       // n*4
    float* denom = s_dst + (size_t)n * 4;       // n*4
    float* rden = denom + (size_t)n * 4;        // n*4
    float* w = rden + (size_t)n * 4;            // e floats

    // Fold the 4-step (q,p) <- (q+0.25p, p-0.25q) recurrence: xt = aq*x + bq*(x@W^T)
    float aq = 1.f, bq = 0.f, ap = 0.f, bp = 1.f;
    for (int i = 0; i < 4; ++i) {
        float naq = aq + 0.25f * ap, nbq = bq + 0.25f * bp;
        float nap = ap - 0.25f * aq, nbp = bp - 0.25f * bq;
        aq = naq; bq = nbq; ap = nap; bp = nbp;
    }

    k_init<<<(n * 64 + 255) / 256, 256, 0, stream>>>(out, denom, n);
    k_node<<<(n + 3) / 4, 256, 0, stream>>>(x, W, a, xt, s_src, s_dst, n, aq, bq);
    k_denom<<<(e + 255) / 256, 256, 0, stream>>>(row, col, s_src, s_dst, denom, e);
    k_rden<<<(n * 4 + 255) / 256, 256, 0, stream>>>(denom, rden, n * 4);
    k_edgew<<<(e + 255) / 256, 256, 0, stream>>>(row, col, s_src, s_dst, rden, w, e);
    k_aggr<<<(e + 3) / 4, 256, 0, stream>>>(row, col, w, xt, out, e);
}

// Round 3
// 721.374 us; speedup vs baseline: 1.2468x; 1.2468x over previous
//
#include <hip/hip_runtime.h>

// HamGraphConvolution: N=100k nodes, D=64 feats, H=4 heads (DK=16), E=1.6M edges.
// xt = c1*x + c2*(x@W^T)  (Hamiltonian 4-step linear recurrence folded on host)
// GAT-style attention normalized over col, aggregated over row.
// Softmax max-subtraction skipped: shift-invariant, eps 1e-16 unreachable.
// R3: row-CSR build (hist+scan+scatter) + wave-per-row gather-reduce replaces
//     the 102.4M-atomic scatter aggregation (R2: k_aggr atomic-pipe bound,
//     294 G atomics/s, 400 MB write-through).

#define LRELU(v) ((v) > 0.0f ? (v) : 0.2f * (v))

// zero denom (n*4 floats) and deg (n ints)
__global__ __launch_bounds__(256) void k_zero(float* __restrict__ denom,
                                              int* __restrict__ deg, int n) {
    int i = blockIdx.x * 256 + threadIdx.x;
    if (i < n * 4) denom[i] = 0.0f;
    if (i < n) deg[i] = 0;
}

__global__ __launch_bounds__(256) void k_node(const float* __restrict__ x,
                                              const float* __restrict__ W,
                                              const float* __restrict__ a,
                                              float* __restrict__ xt,
                                              float* __restrict__ s_src,
                                              float* __restrict__ s_dst,
                                              int n, float c1, float c2) {
    __shared__ float Ws[64 * 65];  // bank (lane+k)%32 -> 2-way (free per m136)
    for (int i = threadIdx.x; i < 64 * 64; i += 256) {
        int r = i >> 6, c = i & 63;
        Ws[r * 65 + c] = W[i];
    }
    __syncthreads();
    int wave = threadIdx.x >> 6;
    int lane = threadIdx.x & 63;
    float a_s = a[lane & 15];
    float a_d = a[16 + (lane & 15)];
    int node = blockIdx.x * 4 + wave;
    if (node >= n) return;

    float xv = x[node * 64 + lane];
    float p = 0.0f;
#pragma unroll
    for (int k = 0; k < 64; ++k) {
        float xk = __shfl(xv, k, 64);  // uniform index -> readlane
        p = fmaf(xk, Ws[lane * 65 + k], p);
    }
    float xtv = c1 * xv + c2 * p;
    xt[node * 64 + lane] = xtv;

    float ss = xtv * a_s;
    float sd = xtv * a_d;
#pragma unroll
    for (int off = 8; off >= 1; off >>= 1) {
        ss += __shfl_xor(ss, off, 64);
        sd += __shfl_xor(sd, off, 64);
    }
    if ((lane & 15) == 0) {
        int h = lane >> 4;
        s_src[node * 4 + h] = ss;
        s_dst[node * 4 + h] = sd;
    }
}

// fused: row-degree histogram + denom accumulation
__global__ __launch_bounds__(256) void k_edge1(const int* __restrict__ row,
                                               const int* __restrict__ col,
                                               const float* __restrict__ s_src,
                                               const float* __restrict__ s_dst,
                                               int* __restrict__ deg,
                                               float* __restrict__ denom, int e) {
    int idx = blockIdx.x * 256 + threadIdx.x;
    if (idx >= e) return;
    int r = row[idx], c = col[idx];
    atomicAdd(&deg[r], 1);
    float4 ss = *(const float4*)(s_src + (size_t)r * 4);
    float4 sd = *(const float4*)(s_dst + (size_t)c * 4);
    atomicAdd(&denom[c * 4 + 0], __expf(LRELU(ss.x + sd.x)));
    atomicAdd(&denom[c * 4 + 1], __expf(LRELU(ss.y + sd.y)));
    atomicAdd(&denom[c * 4 + 2], __expf(LRELU(ss.z + sd.z)));
    atomicAdd(&denom[c * 4 + 3], __expf(LRELU(ss.w + sd.w)));
}

// ---- 3-kernel exclusive scan of deg[n] -> rowptr[n+1], cursor[n] ----
// chunk = 1024 per block (256 threads x 4). nb = ceil(n/1024) <= 256 assumed.
__global__ __launch_bounds__(256) void k_scan1(const int* __restrict__ deg,
                                               int* __restrict__ bsum, int n) {
    __shared__ int s[256];
    int t = threadIdx.x;
    int base = blockIdx.x * 1024 + t * 4;
    int sum = 0;
#pragma unroll
    for (int j = 0; j < 4; ++j) {
        int i = base + j;
        if (i < n) sum += deg[i];
    }
    s[t] = sum;
    __syncthreads();
    for (int d = 128; d >= 1; d >>= 1) {
        if (t < d) s[t] += s[t + d];
        __syncthreads();
    }
    if (t == 0) bsum[blockIdx.x] = s[0];
}

__global__ __launch_bounds__(256) void k_scan2(const int* __restrict__ bsum,
                                               int* __restrict__ bofs,
                                               int* __restrict__ rowptr,
                                               int nb, int n) {
    __shared__ int s[256];
    int t = threadIdx.x;
    s[t] = (t < nb) ? bsum[t] : 0;
    __syncthreads();
    for (int d = 1; d < 256; d <<= 1) {
        int add = (t >= d) ? s[t - d] : 0;
        __syncthreads();
        s[t] += add;
        __syncthreads();
    }
    if (t < nb) bofs[t] = (t == 0) ? 0 : s[t - 1];
    if (t == 255) rowptr[n] = s[255];  // total E
}

__global__ __launch_bounds__(256) void k_scan3(const int* __restrict__ deg,
                                               const int* __restrict__ bofs,
                                               int* __restrict__ rowptr,
                                               int* __restrict__ cursor, int n) {
    __shared__ int s[256];
    int t = threadIdx.x;
    int base = blockIdx.x * 1024 + t * 4;
    int lsum = 0;
#pragma unroll
    for (int j = 0; j < 4; ++j) {
        int i = base + j;
        if (i < n) lsum += deg[i];
    }
    s[t] = lsum;
    __syncthreads();
    for (int d = 1; d < 256; d <<= 1) {
        int add = (t >= d) ? s[t - d] : 0;
        __syncthreads();
        s[t] += add;
        __syncthreads();
    }
    int run = bofs[blockIdx.x] + s[t] - lsum;  // exclusive prefix for this thread
#pragma unroll
    for (int j = 0; j < 4; ++j) {
        int i = base + j;
        if (i < n) {
            rowptr[i] = run;
            cursor[i] = run;
            run += deg[i];
        }
    }
}

__global__ __launch_bounds__(256) void k_rden(const float* __restrict__ denom,
                                              float* __restrict__ rden, int n4) {
    int i = blockIdx.x * 256 + threadIdx.x;
    if (i < n4) rden[i] = 1.0f / (denom[i] + 1e-16f);
}

// compute per-edge w and scatter (col, w) into row-sorted CSR slots
__global__ __launch_bounds__(256) void k_scatter(const int* __restrict__ row,
                                                 const int* __restrict__ col,
                                                 const float* __restrict__ s_src,
                                                 const float* __restrict__ s_dst,
                                                 const float* __restrict__ rden,
                                                 int* __restrict__ cursor,
                                                 int2* __restrict__ cw, int e) {
    int idx = blockIdx.x * 256 + threadIdx.x;
    if (idx >= e) return;
    int r = row[idx], c = col[idx];
    float4 ss = *(const float4*)(s_src + (size_t)r * 4);
    float4 sd = *(const float4*)(s_dst + (size_t)c * 4);
    float4 rd = *(const float4*)(rden + (size_t)c * 4);
    float wv = __expf(LRELU(ss.x + sd.x)) * rd.x +
               __expf(LRELU(ss.y + sd.y)) * rd.y +
               __expf(LRELU(ss.z + sd.z)) * rd.z +
               __expf(LRELU(ss.w + sd.w)) * rd.w;
    wv *= 0.25f;
    int pos = atomicAdd(&cursor[r], 1);
    cw[pos] = make_int2(c, __float_as_int(wv));
}

// wave-per-row gather-reduce: no atomics, each out row written exactly once
__global__ __launch_bounds__(256) void k_aggr_csr(const int* __restrict__ rowptr,
                                                  const int2* __restrict__ cw,
                                                  const float* __restrict__ xt,
                                                  float* __restrict__ out, int n) {
    int r = blockIdx.x * 4 + (threadIdx.x >> 6);
    if (r >= n) return;
    int lane = threadIdx.x & 63;
    int start = rowptr[r], end = rowptr[r + 1];
    float acc = 0.0f;
    for (int base = start; base < end; base += 64) {
        int m = min(64, end - base);
        int cc = 0;
        float ww = 0.0f;
        if (lane < m) {
            int2 v = cw[base + lane];  // coalesced
            cc = v.x;
            ww = __int_as_float(v.y);
        }
        int k = 0;
        for (; k + 4 <= m; k += 4) {  // 4 independent gathers in flight
            int c0 = __shfl(cc, k, 64), c1 = __shfl(cc, k + 1, 64);
            int c2 = __shfl(cc, k + 2, 64), c3 = __shfl(cc, k + 3, 64);
            float w0 = __shfl(ww, k, 64), w1 = __shfl(ww, k + 1, 64);
            float w2 = __shfl(ww, k + 2, 64), w3 = __shfl(ww, k + 3, 64);
            float x0 = xt[(size_t)c0 * 64 + lane];
            float x1 = xt[(size_t)c1 * 64 + lane];
            float x2 = xt[(size_t)c2 * 64 + lane];
            float x3 = xt[(size_t)c3 * 64 + lane];
            acc = fmaf(w0, x0, acc);
            acc = fmaf(w1, x1, acc);
            acc = fmaf(w2, x2, acc);
            acc = fmaf(w3, x3, acc);
        }
        for (; k < m; ++k) {
            int c0 = __shfl(cc, k, 64);
            float w0 = __shfl(ww, k, 64);
            acc = fmaf(w0, xt[(size_t)c0 * 64 + lane], acc);
        }
    }
    out[(size_t)r * 64 + lane] = acc;
}

extern "C" void kernel_launch(void* const* d_in, const int* in_sizes, int n_in,
                              void* d_out, int out_size, void* d_ws, size_t ws_size,
                              hipStream_t stream) {
    const float* x = (const float*)d_in[0];
    const int* ei = (const int*)d_in[1];
    // d_in[2] = edge_weight: unused by the reference
    const float* W = (const float*)d_in[3];
    const float* a = (const float*)d_in[4];
    int n = in_sizes[0] / 64;
    int e = in_sizes[1] / 2;
    const int* row = ei;
    const int* col = ei + e;
    float* out = (float*)d_out;

    // workspace layout (4-byte units)
    float* xt = (float*)d_ws;                    // n*64
    float* s_src = xt + (size_t)n * 64;          // n*4
    float* s_dst = s_src + (size_t)n * 4;        // n*4
    float* denom = s_dst + (size_t)n * 4;        // n*4
    float* rden = denom + (size_t)n * 4;         // n*4
    int* deg = (int*)(rden + (size_t)n * 4);     // n
    int* rowptr = deg + n;                       // n+1
    int* cursor = rowptr + (n + 1);              // n
    int* bsum = cursor + n;                      // 256
    int* bofs = bsum + 256;                      // 256
    size_t ofs = (size_t)(bofs + 256 - (int*)d_ws);
    ofs = (ofs + 1) & ~(size_t)1;                // 8B-align for int2
    int2* cw = (int2*)((int*)d_ws + ofs);        // e int2

    // Fold 4-step (q,p) <- (q+0.25p, p-0.25q): xt = aq*x + bq*(x@W^T)
    float aq = 1.f, bq = 0.f, ap = 0.f, bp = 1.f;
    for (int i = 0; i < 4; ++i) {
        float naq = aq + 0.25f * ap, nbq = bq + 0.25f * bp;
        float nap = ap - 0.25f * aq, nbp = bp - 0.25f * bq;
        aq = naq; bq = nbq; ap = nap; bp = nbp;
    }

    int nb = (n + 1023) / 1024;  // assumes n <= 262144
    k_zero<<<(n * 4 + 255) / 256, 256, 0, stream>>>(denom, deg, n);
    k_node<<<(n + 3) / 4, 256, 0, stream>>>(x, W, a, xt, s_src, s_dst, n, aq, bq);
    k_edge1<<<(e + 255) / 256, 256, 0, stream>>>(row, col, s_src, s_dst, deg, denom, e);
    k_scan1<<<nb, 256, 0, stream>>>(deg, bsum, n);
    k_scan2<<<1, 256, 0, stream>>>(bsum, bofs, rowptr, nb, n);
    k_scan3<<<nb, 256, 0, stream>>>(deg, bofs, rowptr, cursor, n);
    k_rden<<<(n * 4 + 255) / 256, 256, 0, stream>>>(denom, rden, n * 4);
    k_scatter<<<(e + 255) / 256, 256, 0, stream>>>(row, col, s_src, s_dst, rden,
                                                   cursor, cw, e);
    k_aggr_csr<<<(n + 3) / 4, 256, 0, stream>>>(rowptr, cw, xt, out, n);
}